// Round 4
// baseline (559.770 us; speedup 1.0000x reference)
//
#include <hip/hip_runtime.h>

#define NCP   64
#define BTS   16
#define NTPL  2048
#define TSTEPS 6
#define DTF   0.2f         // 1/(T-1)

// ---------- fast scalar helpers ----------
__device__ __forceinline__ float fast_rcp(float x) { return __builtin_amdgcn_rcpf(x); }
__device__ __forceinline__ float fexp2(float x)    { return __builtin_amdgcn_exp2f(x); }
__device__ __forceinline__ float fast_tanh(float x) {
    float e = __expf(2.0f * x);
    return 1.0f - 2.0f * fast_rcp(1.0f + e);
}

// ======================================================================
// Transformed-weight symmetric kernel block evaluator (flow path).
// M = S(x,p)_half + S(p,x)_half (0.5 factors folded into weights):
// full symmetrized 2x2 block [[M00,M01],[M01,M11]].
// wt layout: W1t[40] b1t[10] W2t[100] b2t[10] C0[10] C1[10] C2[10] b3t[3]
// ======================================================================
__device__ __forceinline__ void kblock(
    float x0, float x1, float p0, float p1,
    const float* __restrict__ wt,
    float& M00, float& M01, float& M11)
{
    const float* __restrict__ W1t = wt;
    const float* __restrict__ b1t = wt + 40;
    const float* __restrict__ W2t = wt + 50;
    const float* __restrict__ b2t = wt + 150;
    const float* __restrict__ C0  = wt + 160;
    const float* __restrict__ C1  = wt + 170;
    const float* __restrict__ C2  = wt + 180;
    const float* __restrict__ b3t = wt + 190;

    float ra[10], rb[10];
#pragma unroll
    for (int k = 0; k < 10; ++k) {
        float ta = fmaf(p1, W1t[30 + k],
                   fmaf(p0, W1t[20 + k],
                   fmaf(x1, W1t[10 + k],
                   fmaf(x0, W1t[k], b1t[k]))));
        float tb = fmaf(x1, W1t[30 + k],
                   fmaf(x0, W1t[20 + k],
                   fmaf(p1, W1t[10 + k],
                   fmaf(p0, W1t[k], b1t[k]))));
        ra[k] = fast_rcp(1.0f + fexp2(ta));
        rb[k] = fast_rcp(1.0f + fexp2(tb));
    }
    float ua[10], ub[10];
#pragma unroll
    for (int k = 0; k < 10; ++k) { ua[k] = b2t[k]; ub[k] = b2t[k]; }
#pragma unroll
    for (int c = 0; c < 10; ++c) {
#pragma unroll
        for (int k = 0; k < 10; ++k) {
            float w = W2t[c * 10 + k];
            ua[k] = fmaf(ra[c], w, ua[k]);
            ub[k] = fmaf(rb[c], w, ub[k]);
        }
    }
    float Oa = b3t[0], Ob = b3t[0];
    float T1a = b3t[1], T1b = b3t[1];
    float T2a = b3t[2], T2b = b3t[2];
#pragma unroll
    for (int c = 0; c < 10; ++c) {
        float r2a = fast_rcp(1.0f + fexp2(ua[c]));
        float r2b = fast_rcp(1.0f + fexp2(ub[c]));
        Oa  = fmaf(r2a, C0[c], Oa);   Ob  = fmaf(r2b, C0[c], Ob);
        T1a = fmaf(r2a, C1[c], T1a);  T1b = fmaf(r2b, C1[c], T1b);
        T2a = fmaf(r2a, C2[c], T2a);  T2b = fmaf(r2b, C2[c], T2b);
    }
    M00 = fexp2(T1a) + fexp2(T1b);
    M01 = Oa + Ob;
    M11 = fexp2(T2a) + fexp2(T2b);
}

// ---------- original-weight MLP forward (shoot path, needs h stash) ----------
__device__ __forceinline__ void mlp_fwd_stash(
    float z0, float z1, float z2, float z3,
    const float* __restrict__ W1, const float* __restrict__ b1,
    const float* __restrict__ W2, const float* __restrict__ b2,
    const float* __restrict__ W3, const float* __restrict__ b3,
    float& o0, float& e1, float& e2, float* h1s, float* h2s)
{
    float h1[10];
#pragma unroll
    for (int k = 0; k < 10; ++k) {
        float u = fmaf(z3, W1[30 + k],
                  fmaf(z2, W1[20 + k],
                  fmaf(z1, W1[10 + k],
                  fmaf(z0, W1[k], b1[k]))));
        h1[k] = fast_tanh(u);
        h1s[k] = h1[k];
    }
    float u2[10];
#pragma unroll
    for (int k = 0; k < 10; ++k) u2[k] = b2[k];
#pragma unroll
    for (int c = 0; c < 10; ++c) {
#pragma unroll
        for (int k = 0; k < 10; ++k) u2[k] = fmaf(h1[c], W2[c * 10 + k], u2[k]);
    }
    float o0a = b3[0], o1a = b3[1], o2a = b3[2];
#pragma unroll
    for (int c = 0; c < 10; ++c) {
        float h2 = fast_tanh(u2[c]);
        h2s[c] = h2;
        o0a = fmaf(h2, W3[c * 3 + 0], o0a);
        o1a = fmaf(h2, W3[c * 3 + 1], o1a);
        o2a = fmaf(h2, W3[c * 3 + 2], o2a);
    }
    o0 = o0a;
    e1 = __expf(o1a);
    e2 = __expf(o2a);
}

// ======================================================================
// Fused shooting: 16 batch blocks of 1024 threads (16 waves). Wave wv,
// sub-step loop: a = wv + 16*sub covers all 64 control points; lane = b.
// LDS state + __syncthreads between the 6 symplectic steps.
// Block BTS does the flow-weight transform instead.
// ======================================================================
__global__ __launch_bounds__(1024, 1)
void shoot_all(const float* __restrict__ q0, const float* __restrict__ cp,
               const float* __restrict__ W1, const float* __restrict__ b1,
               const float* __restrict__ W2, const float* __restrict__ b2,
               const float* __restrict__ W3, const float* __restrict__ b3,
               float* __restrict__ p_hist, float* __restrict__ q_hist,
               float* __restrict__ wt)
{
    if (blockIdx.x == BTS) {
        const float L2 = 1.4426950408889634f;   // log2(e)
        int t = threadIdx.x;
        if (t < 40) wt[t] = 2.0f * L2 * W1[t];
        if (t < 10) wt[40 + t] = 2.0f * L2 * b1[t];
        if (t < 100) wt[50 + t] = -4.0f * L2 * W2[t];
        if (t < 10) {
            float s = b2[t];
            for (int c = 0; c < 10; ++c) s += W2[c * 10 + t];
            wt[150 + t] = 2.0f * L2 * s;                 // b2''
            wt[160 + t] = -W3[t * 3 + 0];                // C0 (0.5 * -2)
            wt[170 + t] = -2.0f * L2 * W3[t * 3 + 1];    // C1
            wt[180 + t] = -2.0f * L2 * W3[t * 3 + 2];    // C2
        }
        if (t < 3) {
            float s = b3[t];
            for (int c = 0; c < 10; ++c) s += W3[c * 3 + t];
            wt[190 + t] = (t == 0) ? 0.5f * s : fmaf(L2, s, -1.0f);
        }
        return;
    }

    int batch = blockIdx.x;
    int wv = threadIdx.x >> 6;     // 0..15
    int b  = threadIdx.x & 63;

    __shared__ float P[NCP][2], Q[NCP][2];
    if (threadIdx.x < NCP) {
        int t = threadIdx.x;
        P[t][0] = cp[2 * t];
        P[t][1] = cp[2 * t + 1];
        Q[t][0] = q0[(batch * NCP + t) * 2 + 0];
        Q[t][1] = q0[(batch * NCP + t) * 2 + 1];
    }
    __syncthreads();

    for (int s = 0; s < TSTEPS; ++s) {
        float np[4][2], nq[4][2];     // results for the 4 a's this wave owns

#pragma unroll
        for (int sub = 0; sub < 4; ++sub) {
            int a = wv + (sub << 4);
            float pax = P[a][0], pay = P[a][1];
            float qax = Q[a][0], qay = Q[a][1];
            float pbx = P[b][0], pby = P[b][1];
            float qbx = Q[b][0], qby = Q[b][1];

            float dhq_x = 0.f, dhq_y = 0.f;
            float g_x = 0.f, g_y = 0.f;
            float cross = fmaf(qax, qby, qay * qbx);

#pragma unroll
            for (int e = 0; e < 2; ++e) {
                float z0 = e ? pbx : pax;
                float z1 = e ? pby : pay;
                float z2 = e ? pax : pbx;
                float z3 = e ? pay : pby;

                float h1[10], h2[10];
                float o0, e1, e2;
                mlp_fwd_stash(z0, z1, z2, z3, W1, b1, W2, b2, W3, b3,
                              o0, e1, e2, h1, h2);

                dhq_x = fmaf(0.5f, fmaf(e1, qbx, o0 * qby), dhq_x);
                dhq_y = fmaf(0.5f, fmaf(o0, qbx, e2 * qby), dhq_y);

                float d0 = cross;
                float d1 = e1 * qax * qbx;
                float d2 = e2 * qay * qby;

                float du2[10];
#pragma unroll
                for (int c = 0; c < 10; ++c) {
                    float dh2 = fmaf(W3[c * 3 + 0], d0,
                                fmaf(W3[c * 3 + 1], d1, W3[c * 3 + 2] * d2));
                    du2[c] = dh2 * (1.0f - h2[c] * h2[c]);
                }
                float du1[10];
#pragma unroll
                for (int c = 0; c < 10; ++c) {
                    float dh1 = 0.f;
#pragma unroll
                    for (int k = 0; k < 10; ++k) dh1 = fmaf(W2[c * 10 + k], du2[k], dh1);
                    du1[c] = dh1 * (1.0f - h1[c] * h1[c]);
                }
                int c0 = e ? 2 : 0;
                float ga = 0.f, gb = 0.f;
#pragma unroll
                for (int k = 0; k < 10; ++k) {
                    ga = fmaf(W1[(0 + c0) * 10 + k], du1[k], ga);
                    gb = fmaf(W1[(1 + c0) * 10 + k], du1[k], gb);
                }
                g_x = fmaf(0.5f, ga, g_x);
                g_y = fmaf(0.5f, gb, g_y);
            }

#pragma unroll
            for (int off = 32; off > 0; off >>= 1) {
                dhq_x += __shfl_xor(dhq_x, off);
                dhq_y += __shfl_xor(dhq_y, off);
                g_x   += __shfl_xor(g_x, off);
                g_y   += __shfl_xor(g_y, off);
            }
            np[sub][0] = fmaf(DTF, dhq_x, pax);
            np[sub][1] = fmaf(DTF, dhq_y, pay);
            nq[sub][0] = fmaf(-DTF, g_x, qax);
            nq[sub][1] = fmaf(-DTF, g_y, qay);
        }

        __syncthreads();   // all reads of P,Q done before update
        if (b == 0) {
#pragma unroll
            for (int sub = 0; sub < 4; ++sub) {
                int a = wv + (sub << 4);
                P[a][0] = np[sub][0]; P[a][1] = np[sub][1];
                Q[a][0] = nq[sub][0]; Q[a][1] = nq[sub][1];
                size_t o = (((size_t)(s + 1) * BTS + batch) * NCP + a) * 2;
                p_hist[o] = np[sub][0]; p_hist[o + 1] = np[sub][1];
                q_hist[o] = nq[sub][0]; q_hist[o + 1] = nq[sub][1];
            }
        }
        __syncthreads();
    }
}

// ======================================================================
// Flow step 0: x == tpl and p == cp for ALL batches -> compute the 2x2
// kernel block once per (i,j) and apply all 16 batches' q. Writes x^(1)
// into d_out.
// ======================================================================
__global__ __launch_bounds__(256, 4)
void flow_step0(const float* __restrict__ tpl, const float* __restrict__ cp,
                const float* __restrict__ q0, float* __restrict__ out,
                const float* __restrict__ wt)
{
    int i = blockIdx.x * 4 + (threadIdx.x >> 6);   // template point
    int j = threadIdx.x & 63;

    float x0 = tpl[2 * i], x1 = tpl[2 * i + 1];
    float p0 = cp[2 * j],  p1 = cp[2 * j + 1];

    float M00, M01, M11;
    kblock(x0, x1, p0, p1, wt, M00, M01, M11);

    const float2* __restrict__ q = (const float2*)q0;
#pragma unroll
    for (int bt = 0; bt < BTS; ++bt) {
        float2 qq = q[bt * NCP + j];
        float vx = fmaf(M00, qq.x, M01 * qq.y);
        float vy = fmaf(M01, qq.x, M11 * qq.y);
#pragma unroll
        for (int off = 32; off > 0; off >>= 1) {
            vx += __shfl_xor(vx, off);
            vy += __shfl_xor(vy, off);
        }
        if (j == 0) {
            out[((size_t)bt * NTPL + i) * 2 + 0] = fmaf(DTF, vx, x0);
            out[((size_t)bt * NTPL + i) * 2 + 1] = fmaf(DTF, vy, x1);
        }
    }
}

// ======================================================================
// Flow steps 1..6: wave = (batch, i), lane = control point j. Reads x^(1)
// from d_out, writes final x.
// ======================================================================
__global__ __launch_bounds__(256, 4)
void flow_rest(const float* __restrict__ p_hist, const float* __restrict__ q_hist,
               float* __restrict__ out, const float* __restrict__ wt)
{
    int unit = blockIdx.x * 4 + (threadIdx.x >> 6);
    int j = threadIdx.x & 63;
    int batch = unit >> 11;
    int i = unit & (NTPL - 1);

    const float2* __restrict__ ph = (const float2*)p_hist;
    const float2* __restrict__ qh = (const float2*)q_hist;
    float2 Pv[TSTEPS], Qv[TSTEPS];
#pragma unroll
    for (int s = 0; s < TSTEPS; ++s) {
        int idx = ((s + 1) * BTS + batch) * NCP + j;
        Pv[s] = ph[idx];
        Qv[s] = qh[idx];
    }

    size_t oidx = ((size_t)batch * NTPL + i) * 2;
    float x0 = out[oidx + 0];
    float x1 = out[oidx + 1];

#pragma unroll
    for (int s = 0; s < TSTEPS; ++s) {
        float M00, M01, M11;
        kblock(x0, x1, Pv[s].x, Pv[s].y, wt, M00, M01, M11);
        float vx = fmaf(M00, Qv[s].x, M01 * Qv[s].y);
        float vy = fmaf(M01, Qv[s].x, M11 * Qv[s].y);
#pragma unroll
        for (int off = 32; off > 0; off >>= 1) {
            vx += __shfl_xor(vx, off);
            vy += __shfl_xor(vy, off);
        }
        x0 = fmaf(DTF, vx, x0);
        x1 = fmaf(DTF, vy, x1);
    }

    if (j == 0) {
        out[oidx + 0] = x0;
        out[oidx + 1] = x1;
    }
}

extern "C" void kernel_launch(void* const* d_in, const int* in_sizes, int n_in,
                              void* d_out, int out_size, void* d_ws, size_t ws_size,
                              hipStream_t stream)
{
    const float* q0  = (const float*)d_in[0];   // [16,64,2]
    const float* tpl = (const float*)d_in[1];   // [2048,2]
    const float* cp  = (const float*)d_in[2];   // [64,2]
    const float* W1  = (const float*)d_in[3];   // [4,10]
    const float* b1  = (const float*)d_in[4];   // [10]
    const float* W2  = (const float*)d_in[5];   // [10,10]
    const float* b2  = (const float*)d_in[6];   // [10]
    const float* W3  = (const float*)d_in[7];   // [10,3]
    const float* b3  = (const float*)d_in[8];   // [3]
    float* out = (float*)d_out;

    float* ws = (float*)d_ws;
    const int slab = BTS * NCP * 2;                      // 2048 floats / slice
    float* p_hist = ws;                                  // 7 slabs (slot 0 unused)
    float* q_hist = ws + (size_t)7 * slab;
    float* wt     = ws + (size_t)14 * slab;              // 193 floats

    shoot_all<<<BTS + 1, 1024, 0, stream>>>(q0, cp, W1, b1, W2, b2, W3, b3,
                                            p_hist, q_hist, wt);
    flow_step0<<<NTPL / 4, 256, 0, stream>>>(tpl, cp, q0, out, wt);
    flow_rest<<<BTS * NTPL / 4, 256, 0, stream>>>(p_hist, q_hist, out, wt);
}